// Round 12
// baseline (1818.724 us; speedup 1.0000x reference)
//
#include <hip/hip_runtime.h>
#include <cmath>

#define TT   6
#define NB   128
#define DIM  192
#define SCALE 0.17677669529663687f

typedef __attribute__((ext_vector_type(8))) short v8s;
typedef __attribute__((ext_vector_type(4))) float v4f;

__device__ __forceinline__ short f2bf(float f) {
  union { float f; unsigned u; } v; v.f = f;
  unsigned r = v.u + 0x7fffu + ((v.u >> 16) & 1u);
  return (short)(r >> 16);
}
__device__ __forceinline__ void fence() {
  __asm__ volatile("s_waitcnt lgkmcnt(0)" ::: "memory");
}

// ---- fused prep: bf16 weight conversion + sine position table, one launch ----
__global__ void prep_kernel(const float* __restrict__ Wqkv, const float* __restrict__ Wproj,
                            const float* __restrict__ W1, const float* __restrict__ W2,
                            short* __restrict__ dWqkv, short* __restrict__ dWproj,
                            short* __restrict__ dW1, short* __restrict__ dW2,
                            float* __restrict__ pos) {
  int idx = blockIdx.x * 256 + threadIdx.x;
  const float* src = nullptr; short* dst = nullptr; int off = 0;
  if (idx < 27648)      { src = Wqkv;  dst = dWqkv;  off = idx; }
  else if (idx < 46080) { src = Wproj; dst = dWproj; off = idx - 27648; }
  else if (idx < 55296) { src = W1;    dst = dW1;    off = idx - 46080; }
  else if (idx < 64512) { src = W2;    dst = dW2;    off = idx - 55296; }
  else if (idx < 67584) {
    int p0 = (idx - 64512) * 4;
    float4 r;
    float* rp = (float*)&r;
#pragma unroll
    for (int jj = 0; jj < 4; jj++) {
      int p = p0 + jj;
      int row = p / 192, c = p - row * 192;
      int e  = (c < 96) ? (row >> 3) : (row & 7);
      int cc = (c < 96) ? c : c - 96;
      int m = cc >> 1;
      float embed = (float)(e + 1) * (6.283185307179586f / 8.000001f);
      float dt = powf(10000.0f, (float)m * (1.0f / 48.0f));
      float ang = embed / dt;
      rp[jj] = (cc & 1) ? cosf(ang) : sinf(ang);
    }
    *(float4*)(pos + p0) = r;
    return;
  } else return;
  const float* s = src + off * 4;
  short4 r;
  r.x = f2bf(s[0]); r.y = f2bf(s[1]); r.z = f2bf(s[2]); r.w = f2bf(s[3]);
  *(short4*)(dst + off * 4) = r;
}

// ---- QKV pre-kernel (unchanged, r4-verified XCD swizzle) ----
__global__ __launch_bounds__(256) void qkv_kernel(
    const float* __restrict__ x, const float* __restrict__ pos,
    const short* __restrict__ Wqkv_bf,
    short* __restrict__ Qb, short* __restrict__ Kb, short* __restrict__ Vtb) {
  __shared__ short XP[64 * 200];
  int bid = blockIdx.x;
  int xcd = bid & 7, idx = bid >> 3;
  int bq = idx / TT;
  int b = xcd * 16 + bq, t = idx - bq * TT;
  int tid = threadIdx.x, w = tid >> 6, lane = tid & 63;
  int l15 = lane & 15, quad = lane >> 4;
  const float* xrow = x + (size_t)(b * (TT * 64) + t * 64) * DIM;
  for (int c = tid; c < 64 * 24; c += 256) {
    int row = c / 24, col8 = (c - (c / 24) * 24) * 8;
    const float* xs = xrow + row * DIM + col8;
    const float* pp = pos + row * DIM + col8;
    v8s r8;
#pragma unroll
    for (int jj = 0; jj < 8; jj++) r8[jj] = f2bf(xs[jj] + pp[jj]);
    *(v8s*)(XP + row * 200 + col8) = r8;
  }
  __syncthreads();
  const v4f vzero = {0.f, 0.f, 0.f, 0.f};
  size_t obase = (size_t)(b * TT + t) * 64 * DIM;
#pragma unroll
  for (int cti = 0; cti < 9; cti++) {
    int r0 = w * 144 + cti * 16;
    v4f acc[4] = {vzero, vzero, vzero, vzero};
#pragma unroll
    for (int ks = 0; ks < 6; ks++) {
      v8s a = *(const v8s*)(Wqkv_bf + (size_t)(r0 + l15) * 192 + ks * 32 + quad * 8);
#pragma unroll
      for (int nt = 0; nt < 4; nt++) {
        v8s bb = *(const v8s*)(XP + (nt * 16 + l15) * 200 + ks * 32 + quad * 8);
        acc[nt] = __builtin_amdgcn_mfma_f32_16x16x32_bf16(a, bb, acc[nt], 0, 0, 0);
      }
    }
    int R = r0 + quad * 4;
#pragma unroll
    for (int nt = 0; nt < 4; nt++) {
      int hw = nt * 16 + l15;
      if (R < 192) {
        short4 s;
        s.x = f2bf(acc[nt][0] * SCALE); s.y = f2bf(acc[nt][1] * SCALE);
        s.z = f2bf(acc[nt][2] * SCALE); s.w = f2bf(acc[nt][3] * SCALE);
        *(short4*)(Qb + obase + (size_t)hw * 192 + R) = s;
      } else if (R < 384) {
        short4 s;
        s.x = f2bf(acc[nt][0]); s.y = f2bf(acc[nt][1]);
        s.z = f2bf(acc[nt][2]); s.w = f2bf(acc[nt][3]);
        *(short4*)(Kb + obase + (size_t)hw * 192 + (R - 192)) = s;
      } else {
#pragma unroll
        for (int r = 0; r < 4; r++)
          Vtb[obase + (size_t)(R - 384 + r) * 64 + hw] = f2bf(acc[nt][r]);
      }
    }
  }
}

// register P-transpose (r4/r9-verified): S[4]*inv -> PV B fragments
__device__ __forceinline__ void ptrans(const v4f S[4], float inv,
                                       int srcA, int srcB, bool hiq,
                                       v8s& B0v, v8s& B1v) {
  unsigned pk00, pk01, pk10, pk11, pk20, pk21, pk30, pk31;
  {
    float a0 = S[0][0] * inv, a1 = S[0][1] * inv, a2 = S[0][2] * inv, a3 = S[0][3] * inv;
    __asm__("v_cvt_pk_bf16_f32 %0, %1, %2" : "=v"(pk00) : "v"(a0), "v"(a1));
    __asm__("v_cvt_pk_bf16_f32 %0, %1, %2" : "=v"(pk01) : "v"(a2), "v"(a3));
    float b0 = S[1][0] * inv, b1_ = S[1][1] * inv, b2_ = S[1][2] * inv, b3 = S[1][3] * inv;
    __asm__("v_cvt_pk_bf16_f32 %0, %1, %2" : "=v"(pk10) : "v"(b0), "v"(b1_));
    __asm__("v_cvt_pk_bf16_f32 %0, %1, %2" : "=v"(pk11) : "v"(b2_), "v"(b3));
    float c0 = S[2][0] * inv, c1 = S[2][1] * inv, c2 = S[2][2] * inv, c3 = S[2][3] * inv;
    __asm__("v_cvt_pk_bf16_f32 %0, %1, %2" : "=v"(pk20) : "v"(c0), "v"(c1));
    __asm__("v_cvt_pk_bf16_f32 %0, %1, %2" : "=v"(pk21) : "v"(c2), "v"(c3));
    float d0 = S[3][0] * inv, d1 = S[3][1] * inv, d2 = S[3][2] * inv, d3 = S[3][3] * inv;
    __asm__("v_cvt_pk_bf16_f32 %0, %1, %2" : "=v"(pk30) : "v"(d0), "v"(d1));
    __asm__("v_cvt_pk_bf16_f32 %0, %1, %2" : "=v"(pk31) : "v"(d2), "v"(d3));
  }
  union { unsigned u[4]; v8s v; } B0, B1;
  unsigned ta, tb;
  ta = (unsigned)__shfl((int)pk00, srcA); tb = (unsigned)__shfl((int)pk10, srcA);
  B0.u[0] = hiq ? tb : ta;
  ta = (unsigned)__shfl((int)pk01, srcA); tb = (unsigned)__shfl((int)pk11, srcA);
  B0.u[1] = hiq ? tb : ta;
  ta = (unsigned)__shfl((int)pk00, srcB); tb = (unsigned)__shfl((int)pk10, srcB);
  B0.u[2] = hiq ? tb : ta;
  ta = (unsigned)__shfl((int)pk01, srcB); tb = (unsigned)__shfl((int)pk11, srcB);
  B0.u[3] = hiq ? tb : ta;
  ta = (unsigned)__shfl((int)pk20, srcA); tb = (unsigned)__shfl((int)pk30, srcA);
  B1.u[0] = hiq ? tb : ta;
  ta = (unsigned)__shfl((int)pk21, srcA); tb = (unsigned)__shfl((int)pk31, srcA);
  B1.u[1] = hiq ? tb : ta;
  ta = (unsigned)__shfl((int)pk20, srcB); tb = (unsigned)__shfl((int)pk30, srcB);
  B1.u[2] = hiq ? tb : ta;
  ta = (unsigned)__shfl((int)pk21, srcB); tb = (unsigned)__shfl((int)pk31, srcB);
  B1.u[3] = hiq ? tb : ta;
  B0v = B0.v; B1v = B1.v;
}

// ---- attention precompute: one block per (i,j,b,half), 4 waves, NO LDS, NO barriers.
// Wave (qt=w&1, hg=w>>1): 16 q-rows x 3 heads. Writes O[(i*TT+j)*NB+b][qrow][ch] bf16.
// 9216 blocks x 4 waves = 36 waves/SIMD of work: latency hidden by raw TLP.
__global__ __launch_bounds__(256, 4) void attn_all(
    const short* __restrict__ Qb, const short* __restrict__ Kb,
    const short* __restrict__ Vtb, short* __restrict__ Ob) {
  int bid = blockIdx.x;
  int xcd = bid & 7, idx = bid >> 3;       // 1152 per XCD
  int bq = idx / 72;
  int rem = idx - bq * 72;
  int ij = rem >> 1, half = rem & 1;
  int i = ij / TT, j = ij - i * TT;
  int b = xcd * 16 + bq;

  int tid = threadIdx.x, w = tid >> 6, lane = tid & 63;
  int l15 = lane & 15, quad = lane >> 4;
  int qt = w & 1, hg = w >> 1;
  const v4f vzero = {0.f, 0.f, 0.f, 0.f};

  const short* Qi = Qb + (size_t)(b * TT + i) * 64 * DIM;
  const short* Kj = Kb + (size_t)(b * TT + j) * 64 * DIM;
  const short* Vj = Vtb + (size_t)(b * TT + j) * 64 * DIM;
  short* Oj = Ob + ((size_t)(i * TT + j) * NB + b) * 64 * DIM;

  int qrow = half * 32 + qt * 16 + l15;
  v8s qa[3];
#pragma unroll
  for (int hh = 0; hh < 3; hh++)
    qa[hh] = *(const v8s*)(Qi + (size_t)qrow * 192 + (hg * 3 + hh) * 32 + quad * 8);

  int srcA = l15 + ((lane & 16) << 1);
  int srcB = srcA + 16;
  bool hiq = (lane & 32) != 0;

#pragma unroll
  for (int hh = 0; hh < 3; hh++) {
    int h = hg * 3 + hh;
    v8s kf[4];
#pragma unroll
    for (int cta = 0; cta < 4; cta++)
      kf[cta] = *(const v8s*)(Kj + (size_t)(cta * 16 + l15) * 192 + h * 32 + quad * 8);
    v4f S[4];
#pragma unroll
    for (int cta = 0; cta < 4; cta++)
      S[cta] = __builtin_amdgcn_mfma_f32_16x16x32_bf16(kf[cta], qa[hh], vzero, 0, 0, 0);
    v8s vf0a = *(const v8s*)(Vj + (size_t)(h * 32 + l15) * 64 + quad * 8);
    v8s vf0b = *(const v8s*)(Vj + (size_t)(h * 32 + l15) * 64 + 32 + quad * 8);
    v8s vf1a = *(const v8s*)(Vj + (size_t)(h * 32 + 16 + l15) * 64 + quad * 8);
    v8s vf1b = *(const v8s*)(Vj + (size_t)(h * 32 + 16 + l15) * 64 + 32 + quad * 8);
    float mx = -1e30f;
#pragma unroll
    for (int cta = 0; cta < 4; cta++)
#pragma unroll
      for (int r = 0; r < 4; r++) mx = fmaxf(mx, S[cta][r]);
    mx = fmaxf(mx, __shfl_xor(mx, 16, 64));
    mx = fmaxf(mx, __shfl_xor(mx, 32, 64));
    float sum = 0.f;
#pragma unroll
    for (int cta = 0; cta < 4; cta++)
#pragma unroll
      for (int r = 0; r < 4; r++) {
        float e = __expf(S[cta][r] - mx);
        S[cta][r] = e; sum += e;
      }
    sum += __shfl_xor(sum, 16, 64);
    sum += __shfl_xor(sum, 32, 64);
    float inv = 1.0f / sum;
    v8s B0, B1;
    ptrans(S, inv, srcA, srcB, hiq, B0, B1);
    v4f o0 = __builtin_amdgcn_mfma_f32_16x16x32_bf16(vf0a, B0, vzero, 0, 0, 0);
    o0 = __builtin_amdgcn_mfma_f32_16x16x32_bf16(vf0b, B1, o0, 0, 0, 0);
    short4 s0;
    s0.x = f2bf(o0[0]); s0.y = f2bf(o0[1]); s0.z = f2bf(o0[2]); s0.w = f2bf(o0[3]);
    *(short4*)(Oj + (size_t)qrow * 192 + h * 32 + quad * 4) = s0;
    v4f o1 = __builtin_amdgcn_mfma_f32_16x16x32_bf16(vf1a, B0, vzero, 0, 0, 0);
    o1 = __builtin_amdgcn_mfma_f32_16x16x32_bf16(vf1b, B1, o1, 0, 0, 0);
    short4 s1;
    s1.x = f2bf(o1[0]); s1.y = f2bf(o1[1]); s1.z = f2bf(o1[2]); s1.w = f2bf(o1[3]);
    *(short4*)(Oj + (size_t)qrow * 192 + h * 32 + 16 + quad * 4) = s1;
  }
}

// ---- MLP kernel: one block per (i,b), 4 independent waves; wave w owns rows
// w*16..w*16+15 with ALL 192 channels (12 cti tiles). LayerNorm is fully in-wave
// (48 per-lane elems + 2 shfls = all 192 ch for row l15); y1n/h transposes go
// through a per-wave-PRIVATE LDS strip with lgkmcnt waits only.
// ZERO __syncthreads in this kernel -- no phase convoy possible (the ~460us
// invariant survived every phase-locked variant; this removes the structure).
// O consumed directly from global as B-fragments, prefetched one j ahead.
__global__ __launch_bounds__(256, 2) void mlp_all(
    const float* __restrict__ x, const short* __restrict__ Ob,
    const short* __restrict__ Wproj_bf, const short* __restrict__ W1_bf,
    const short* __restrict__ W2_bf,
    const float* __restrict__ bproj, const float* __restrict__ gamma,
    const float* __restrict__ beta, const float* __restrict__ b1,
    const float* __restrict__ b2,
    float* __restrict__ out) {
  __shared__ short STR[4][16 * 200];   // per-wave private transpose strip

  int bid = blockIdx.x;
  int xcd = bid & 7, idx = bid >> 3;   // 96 per XCD
  int bq = idx / TT;
  int b = xcd * 16 + bq, i = idx - bq * TT;

  int tid = threadIdx.x, w = tid >> 6, lane = tid & 63;
  int l15 = lane & 15, quad = lane >> 4;
  short* strip = STR[w];
  int row = w * 16 + l15;              // this lane's hw row within (i,b)
  const v4f vzero = {0.f, 0.f, 0.f, 0.f};

  // xi fragments (j-invariant): bf16 of x.view rows, built per-lane from f32
  const float* xrow_i = x + ((size_t)(i * NB + b) * 64 + row) * DIM;
  v8s xif[6];
#pragma unroll
  for (int ks = 0; ks < 6; ks++) {
    const float* xs = xrow_i + ks * 32 + quad * 8;
    v8s r8;
#pragma unroll
    for (int e = 0; e < 8; e++) r8[e] = f2bf(xs[e]);
    xif[ks] = r8;
  }

  v4f acc[12];
#pragma unroll
  for (int cti = 0; cti < 12; cti++) acc[cti] = vzero;

  const size_t ostride = (size_t)NB * 64 * DIM;   // per-j O stride
  const short* Obase = Ob + ((size_t)(i * TT) * NB + b) * 64 * DIM + (size_t)row * 192;

  // prologue: O fragments for j=0
  v8s of[6];
#pragma unroll
  for (int ks = 0; ks < 6; ks++)
    of[ks] = *(const v8s*)(Obase + ks * 32 + quad * 8);

  for (int j = 0; j < TT; j++) {
    // ---- G1: y1 = Wproj . [o | xi]^T  (k=384, 144 MFMA) ----
    v4f y1[12];
#pragma unroll
    for (int cti = 0; cti < 12; cti++) y1[cti] = vzero;
#pragma unroll
    for (int g = 0; g < 12; g++) {
      v8s bf = (g < 6) ? of[g] : xif[g - 6];
#pragma unroll
      for (int cti = 0; cti < 12; cti++) {
        v8s a = *(const v8s*)(Wproj_bf + (size_t)(cti * 16 + l15) * 384 + g * 32 + quad * 8);
        y1[cti] = __builtin_amdgcn_mfma_f32_16x16x32_bf16(a, bf, y1[cti], 0, 0, 0);
      }
    }
    // prefetch next j's O fragments (lands under LN+G2+G3)
    if (j < TT - 1) {
      const short* On = Obase + (size_t)(j + 1) * ostride;
#pragma unroll
      for (int ks = 0; ks < 6; ks++)
        of[ks] = *(const v8s*)(On + ks * 32 + quad * 8);
    }
    // ---- bias + in-wave LayerNorm (lane holds all its row's 48 ch; 2 shfls = 192) ----
    float s1 = 0.f, s2 = 0.f;
#pragma unroll
    for (int cti = 0; cti < 12; cti++) {
      float4 bp4 = *(const float4*)(bproj + cti * 16 + quad * 4);
      y1[cti][0] += bp4.x; y1[cti][1] += bp4.y;
      y1[cti][2] += bp4.z; y1[cti][3] += bp4.w;
#pragma unroll
      for (int r = 0; r < 4; r++) { float v = y1[cti][r]; s1 += v; s2 += v * v; }
    }
    s1 += __shfl_xor(s1, 16, 64); s2 += __shfl_xor(s2, 16, 64);
    s1 += __shfl_xor(s1, 32, 64); s2 += __shfl_xor(s2, 32, 64);
    float mu = s1 * (1.0f / 192.0f);
    float rs = rsqrtf(s2 * (1.0f / 192.0f) - mu * mu + 1e-5f);
#pragma unroll
    for (int cti = 0; cti < 12; cti++) {
      float4 g4 = *(const float4*)(gamma + cti * 16 + quad * 4);
      float4 be4 = *(const float4*)(beta + cti * 16 + quad * 4);
      short4 s;
      s.x = f2bf((y1[cti][0] - mu) * rs * g4.x + be4.x);
      s.y = f2bf((y1[cti][1] - mu) * rs * g4.y + be4.y);
      s.z = f2bf((y1[cti][2] - mu) * rs * g4.z + be4.z);
      s.w = f2bf((y1[cti][3] - mu) * rs * g4.w + be4.w);
      *(short4*)(&strip[l15 * 200 + cti * 16 + quad * 4]) = s;
    }
    fence();                            // strip writes visible (same wave)
    v8s bh[6];
#pragma unroll
    for (int ks = 0; ks < 6; ks++)
      bh[ks] = *(const v8s*)(&strip[l15 * 200 + ks * 32 + quad * 8]);
    // ---- G2: y2 = W1 . y1n^T (72 MFMA) ----
    v4f y2[12];
#pragma unroll
    for (int cti = 0; cti < 12; cti++) y2[cti] = vzero;
#pragma unroll
    for (int ks = 0; ks < 6; ks++)
#pragma unroll
      for (int cti = 0; cti < 12; cti++) {
        v8s a = *(const v8s*)(W1_bf + (size_t)(cti * 16 + l15) * 192 + ks * 32 + quad * 8);
        y2[cti] = __builtin_amdgcn_mfma_f32_16x16x32_bf16(a, bh[ks], y2[cti], 0, 0, 0);
      }
    fence();                            // bh reads retired before strip overwrite
    // ---- gelu -> strip ----
#pragma unroll
    for (int cti = 0; cti < 12; cti++) {
      float4 b14 = *(const float4*)(b1 + cti * 16 + quad * 4);
      float vv[4] = {y2[cti][0] + b14.x, y2[cti][1] + b14.y,
                     y2[cti][2] + b14.z, y2[cti][3] + b14.w};
      short sv[4];
#pragma unroll
      for (int r = 0; r < 4; r++) {
        float v = vv[r];
        float t = 0.79788456080286536f * (v + 0.044715f * v * v * v);
        float e = __expf(2.0f * t);
        float th = 1.0f - 2.0f / (e + 1.0f);
        sv[r] = f2bf(0.5f * v * (1.0f + th));
      }
      short4 s;
      s.x = sv[0]; s.y = sv[1]; s.z = sv[2]; s.w = sv[3];
      *(short4*)(&strip[l15 * 200 + cti * 16 + quad * 4]) = s;
    }
    fence();
    v8s hh[6];
#pragma unroll
    for (int ks = 0; ks < 6; ks++)
      hh[ks] = *(const v8s*)(&strip[l15 * 200 + ks * 32 + quad * 8]);
    // ---- G3: acc += W2 . h^T (72 MFMA) ----
#pragma unroll
    for (int ks = 0; ks < 6; ks++)
#pragma unroll
      for (int cti = 0; cti < 12; cti++) {
        v8s a = *(const v8s*)(W2_bf + (size_t)(cti * 16 + l15) * 192 + ks * 32 + quad * 8);
        acc[cti] = __builtin_amdgcn_mfma_f32_16x16x32_bf16(a, hh[ks], acc[cti], 0, 0, 0);
      }
    fence();                            // hh reads retired before next-j strip writes
  }

  // ---- epilogue: direct stores; lane covers all 192 ch of its row in 12 chunks ----
  size_t nrow = (size_t)b * 384 + (size_t)i * 64 + row;
#pragma unroll
  for (int cti = 0; cti < 12; cti++) {
    int ch = cti * 16 + quad * 4;
    float4 xv = *(const float4*)(x + nrow * DIM + ch);
    float4 b24 = *(const float4*)(b2 + ch);
    float4 o4;
    o4.x = xv.x + acc[cti][0] * (1.0f / 6.0f) + b24.x;
    o4.y = xv.y + acc[cti][1] * (1.0f / 6.0f) + b24.y;
    o4.z = xv.z + acc[cti][2] * (1.0f / 6.0f) + b24.z;
    o4.w = xv.w + acc[cti][3] * (1.0f / 6.0f) + b24.w;
    *(float4*)(out + nrow * 384 + ch) = xv;           // x half bit-exact
    *(float4*)(out + nrow * 384 + 192 + ch) = o4;
  }
}

extern "C" void kernel_launch(void* const* d_in, const int* in_sizes, int n_in,
                              void* d_out, int out_size, void* d_ws, size_t ws_size,
                              hipStream_t stream) {
  (void)in_sizes; (void)n_in; (void)out_size; (void)ws_size;
  const float* x     = (const float*)d_in[0];
  const float* Wqkv  = (const float*)d_in[1];
  const float* Wproj = (const float*)d_in[2];
  const float* bproj = (const float*)d_in[3];
  const float* gamma = (const float*)d_in[4];
  const float* beta  = (const float*)d_in[5];
  const float* W1    = (const float*)d_in[6];
  const float* b1    = (const float*)d_in[7];
  const float* W2    = (const float*)d_in[8];
  const float* b2    = (const float*)d_in[9];
  float* out = (float*)d_out;

  // workspace: weights bf16 + pos f32 + Q/K/Vt bf16 + O bf16 (113.2 MB)
  short* Wqkv_bf  = (short*)d_ws;                 // 576*192
  short* Wproj_bf = Wqkv_bf + 110592;             // 192*384
  short* W1_bf    = Wproj_bf + 73728;             // 192*192
  short* W2_bf    = W1_bf + 36864;                // 192*192
  float* pos_f    = (float*)(W2_bf + 36864);      // 64*192 f32
  short* Qb       = (short*)(pos_f + 12288);      // [b][t][hw][ch]
  short* Kb       = Qb + 9437184;                 // [b][t][hw][ch]
  short* Vtb      = Kb + 9437184;                 // [b][t][ch][hw]
  short* Ob       = Vtb + 9437184;                // [ij][b][hw][ch] 56,623,104 shorts

  prep_kernel<<<dim3(264), dim3(256), 0, stream>>>(
      Wqkv, Wproj, W1, W2, Wqkv_bf, Wproj_bf, W1_bf, W2_bf, pos_f);
  qkv_kernel<<<dim3(TT * NB), dim3(256), 0, stream>>>(x, pos_f, Wqkv_bf, Qb, Kb, Vtb);
  attn_all<<<dim3(TT * TT * NB * 2), dim3(256), 0, stream>>>(Qb, Kb, Vtb, Ob);
  mlp_all<<<dim3(TT * NB), dim3(256), 0, stream>>>(
      x, Ob, Wproj_bf, W1_bf, W2_bf, bproj, gamma, beta, b1, b2, out);
}

// Round 13
// 717.062 us; speedup vs baseline: 2.5364x; 2.5364x over previous
//
#include <hip/hip_runtime.h>
#include <cmath>

#define TT   6
#define NB   128
#define DIM  192
#define SCALE 0.17677669529663687f

typedef __attribute__((ext_vector_type(8))) short v8s;
typedef __attribute__((ext_vector_type(4))) float v4f;

__device__ __forceinline__ short f2bf(float f) {
  union { float f; unsigned u; } v; v.f = f;
  unsigned r = v.u + 0x7fffu + ((v.u >> 16) & 1u);
  return (short)(r >> 16);
}

// ---- fused prep: bf16 weight conversion + sine position table, one launch ----
__global__ void prep_kernel(const float* __restrict__ Wqkv, const float* __restrict__ Wproj,
                            const float* __restrict__ W1, const float* __restrict__ W2,
                            short* __restrict__ dWqkv, short* __restrict__ dWproj,
                            short* __restrict__ dW1, short* __restrict__ dW2,
                            float* __restrict__ pos) {
  int idx = blockIdx.x * 256 + threadIdx.x;
  const float* src = nullptr; short* dst = nullptr; int off = 0;
  if (idx < 27648)      { src = Wqkv;  dst = dWqkv;  off = idx; }
  else if (idx < 46080) { src = Wproj; dst = dWproj; off = idx - 27648; }
  else if (idx < 55296) { src = W1;    dst = dW1;    off = idx - 46080; }
  else if (idx < 64512) { src = W2;    dst = dW2;    off = idx - 55296; }
  else if (idx < 67584) {
    int p0 = (idx - 64512) * 4;
    float4 r;
    float* rp = (float*)&r;
#pragma unroll
    for (int jj = 0; jj < 4; jj++) {
      int p = p0 + jj;
      int row = p / 192, c = p - row * 192;
      int e  = (c < 96) ? (row >> 3) : (row & 7);
      int cc = (c < 96) ? c : c - 96;
      int m = cc >> 1;
      float embed = (float)(e + 1) * (6.283185307179586f / 8.000001f);
      float dt = powf(10000.0f, (float)m * (1.0f / 48.0f));
      float ang = embed / dt;
      rp[jj] = (cc & 1) ? cosf(ang) : sinf(ang);
    }
    *(float4*)(pos + p0) = r;
    return;
  } else return;
  const float* s = src + off * 4;
  short4 r;
  r.x = f2bf(s[0]); r.y = f2bf(s[1]); r.z = f2bf(s[2]); r.w = f2bf(s[3]);
  *(short4*)(dst + off * 4) = r;
}

// ---- QKV pre-kernel (unchanged, r4-verified XCD swizzle) ----
__global__ __launch_bounds__(256) void qkv_kernel(
    const float* __restrict__ x, const float* __restrict__ pos,
    const short* __restrict__ Wqkv_bf,
    short* __restrict__ Qb, short* __restrict__ Kb, short* __restrict__ Vtb) {
  __shared__ short XP[64 * 200];
  int bid = blockIdx.x;
  int xcd = bid & 7, idx = bid >> 3;
  int bq = idx / TT;
  int b = xcd * 16 + bq, t = idx - bq * TT;
  int tid = threadIdx.x, w = tid >> 6, lane = tid & 63;
  int l15 = lane & 15, quad = lane >> 4;
  const float* xrow = x + (size_t)(b * (TT * 64) + t * 64) * DIM;
  for (int c = tid; c < 64 * 24; c += 256) {
    int row = c / 24, col8 = (c - (c / 24) * 24) * 8;
    const float* xs = xrow + row * DIM + col8;
    const float* pp = pos + row * DIM + col8;
    v8s r8;
#pragma unroll
    for (int jj = 0; jj < 8; jj++) r8[jj] = f2bf(xs[jj] + pp[jj]);
    *(v8s*)(XP + row * 200 + col8) = r8;
  }
  __syncthreads();
  const v4f vzero = {0.f, 0.f, 0.f, 0.f};
  size_t obase = (size_t)(b * TT + t) * 64 * DIM;
#pragma unroll
  for (int cti = 0; cti < 9; cti++) {
    int r0 = w * 144 + cti * 16;
    v4f acc[4] = {vzero, vzero, vzero, vzero};
#pragma unroll
    for (int ks = 0; ks < 6; ks++) {
      v8s a = *(const v8s*)(Wqkv_bf + (size_t)(r0 + l15) * 192 + ks * 32 + quad * 8);
#pragma unroll
      for (int nt = 0; nt < 4; nt++) {
        v8s bb = *(const v8s*)(XP + (nt * 16 + l15) * 200 + ks * 32 + quad * 8);
        acc[nt] = __builtin_amdgcn_mfma_f32_16x16x32_bf16(a, bb, acc[nt], 0, 0, 0);
      }
    }
    int R = r0 + quad * 4;
#pragma unroll
    for (int nt = 0; nt < 4; nt++) {
      int hw = nt * 16 + l15;
      if (R < 192) {
        short4 s;
        s.x = f2bf(acc[nt][0] * SCALE); s.y = f2bf(acc[nt][1] * SCALE);
        s.z = f2bf(acc[nt][2] * SCALE); s.w = f2bf(acc[nt][3] * SCALE);
        *(short4*)(Qb + obase + (size_t)hw * 192 + R) = s;
      } else if (R < 384) {
        short4 s;
        s.x = f2bf(acc[nt][0]); s.y = f2bf(acc[nt][1]);
        s.z = f2bf(acc[nt][2]); s.w = f2bf(acc[nt][3]);
        *(short4*)(Kb + obase + (size_t)hw * 192 + (R - 192)) = s;
      } else {
#pragma unroll
        for (int r = 0; r < 4; r++)
          Vtb[obase + (size_t)(R - 384 + r) * 64 + hw] = f2bf(acc[nt][r]);
      }
    }
  }
}

// register P-transpose (r4/r9-verified): S[4]*inv -> PV B fragments
__device__ __forceinline__ void ptrans(const v4f S[4], float inv,
                                       int srcA, int srcB, bool hiq,
                                       v8s& B0v, v8s& B1v) {
  unsigned pk00, pk01, pk10, pk11, pk20, pk21, pk30, pk31;
  {
    float a0 = S[0][0] * inv, a1 = S[0][1] * inv, a2 = S[0][2] * inv, a3 = S[0][3] * inv;
    __asm__("v_cvt_pk_bf16_f32 %0, %1, %2" : "=v"(pk00) : "v"(a0), "v"(a1));
    __asm__("v_cvt_pk_bf16_f32 %0, %1, %2" : "=v"(pk01) : "v"(a2), "v"(a3));
    float b0 = S[1][0] * inv, b1_ = S[1][1] * inv, b2_ = S[1][2] * inv, b3 = S[1][3] * inv;
    __asm__("v_cvt_pk_bf16_f32 %0, %1, %2" : "=v"(pk10) : "v"(b0), "v"(b1_));
    __asm__("v_cvt_pk_bf16_f32 %0, %1, %2" : "=v"(pk11) : "v"(b2_), "v"(b3));
    float c0 = S[2][0] * inv, c1 = S[2][1] * inv, c2 = S[2][2] * inv, c3 = S[2][3] * inv;
    __asm__("v_cvt_pk_bf16_f32 %0, %1, %2" : "=v"(pk20) : "v"(c0), "v"(c1));
    __asm__("v_cvt_pk_bf16_f32 %0, %1, %2" : "=v"(pk21) : "v"(c2), "v"(c3));
    float d0 = S[3][0] * inv, d1 = S[3][1] * inv, d2 = S[3][2] * inv, d3 = S[3][3] * inv;
    __asm__("v_cvt_pk_bf16_f32 %0, %1, %2" : "=v"(pk30) : "v"(d0), "v"(d1));
    __asm__("v_cvt_pk_bf16_f32 %0, %1, %2" : "=v"(pk31) : "v"(d2), "v"(d3));
  }
  union { unsigned u[4]; v8s v; } B0, B1;
  unsigned ta, tb;
  ta = (unsigned)__shfl((int)pk00, srcA); tb = (unsigned)__shfl((int)pk10, srcA);
  B0.u[0] = hiq ? tb : ta;
  ta = (unsigned)__shfl((int)pk01, srcA); tb = (unsigned)__shfl((int)pk11, srcA);
  B0.u[1] = hiq ? tb : ta;
  ta = (unsigned)__shfl((int)pk00, srcB); tb = (unsigned)__shfl((int)pk10, srcB);
  B0.u[2] = hiq ? tb : ta;
  ta = (unsigned)__shfl((int)pk01, srcB); tb = (unsigned)__shfl((int)pk11, srcB);
  B0.u[3] = hiq ? tb : ta;
  ta = (unsigned)__shfl((int)pk20, srcA); tb = (unsigned)__shfl((int)pk30, srcA);
  B1.u[0] = hiq ? tb : ta;
  ta = (unsigned)__shfl((int)pk21, srcA); tb = (unsigned)__shfl((int)pk31, srcA);
  B1.u[1] = hiq ? tb : ta;
  ta = (unsigned)__shfl((int)pk20, srcB); tb = (unsigned)__shfl((int)pk30, srcB);
  B1.u[2] = hiq ? tb : ta;
  ta = (unsigned)__shfl((int)pk21, srcB); tb = (unsigned)__shfl((int)pk31, srcB);
  B1.u[3] = hiq ? tb : ta;
  B0v = B0.v; B1v = B1.v;
}

// ---- main fused kernel: one block per (i,b,half), 256 threads (4 waves), 32 hw rows.
// r9 base with the two persistent register caches removed to raise occupancy:
//  - y1x hoist dropped (-24 AGPR): Wproj.xi half of G1 recomputed per j with
//    B-fragments built per-lane from global x (frag-build verified in r12).
//  - qa hoist dropped (-12 VGPR): Q fragments reloaded per head from L2-hot Qi.
// __launch_bounds__(256,4) forces combined VGPR+AGPR <= 128 -> 16 waves/CU.
// Theory: r9's waves stall ~450K/500K cycles on serial L2 chains at ~12 waves/CU;
// TLP is the remaining unexplored lever (ILP attempts all hit the register wall).
__global__ __launch_bounds__(256, 4) void fused_all(
    const float* __restrict__ x,
    const short* __restrict__ Qb, const short* __restrict__ Kb,
    const short* __restrict__ Vtb,
    const short* __restrict__ Wproj_bf, const short* __restrict__ W1_bf,
    const short* __restrict__ W2_bf,
    const float* __restrict__ bproj, const float* __restrict__ gamma,
    const float* __restrict__ beta, const float* __restrict__ b1,
    const float* __restrict__ b2,
    float* __restrict__ out) {
  __shared__ short SP[32 * 200];     // o / y1n; f32 acc staging in epilogue
  __shared__ short HB[32 * 200];     // gelu output h
  __shared__ float LNp[32][4][2];    // LN partials: [row][wc][s1,s2]

  int bid = blockIdx.x;
  int xcd = bid & 7, idx = bid >> 3;     // 192 per XCD
  int bq = idx / 12;
  int rem = idx - bq * 12;
  int i = rem >> 1, half = rem & 1;
  int b = xcd * 16 + bq;

  int tid = threadIdx.x, w = tid >> 6, lane = tid & 63;
  int l15 = lane & 15, quad = lane >> 4;
  int wc = w;                        // GEMM channel slice
  int qt = w & 1, hg = w >> 1;       // attention: q-tile, head-group
  int cb = wc * 48;
  const v4f vzero = {0.f, 0.f, 0.f, 0.f};

  const short* Qi = Qb + (size_t)(b * TT + i) * 64 * DIM;
  int qrow = half * 32 + qt * 16 + l15;

  v4f acc[3][2];
#pragma unroll
  for (int cti = 0; cti < 3; cti++)
#pragma unroll
    for (int nt = 0; nt < 2; nt++) acc[cti][nt] = vzero;

  int srcA = l15 + ((lane & 16) << 1);   // l15 + 32*(quad&1)
  int srcB = srcA + 16;
  bool hiq = (lane & 32) != 0;           // quad >= 2

  // per-lane global row pointers for the xi-fragment rebuild (nt=0,1)
  const float* xr0 = x + ((size_t)(i * NB + b) * 64 + half * 32 + l15) * DIM;
  const float* xr1 = xr0 + 16 * DIM;

  for (int j = 0; j < TT; j++) {
    __syncthreads();               // A: SP free for o (prior G2 reads done)
    {
      const short* Kj = Kb + (size_t)(b * TT + j) * 64 * DIM;
      const short* Vj = Vtb + (size_t)(b * TT + j) * 64 * DIM;
#pragma unroll
      for (int hh = 0; hh < 3; hh++) {
        int h = hg * 3 + hh;
        v8s qa = *(const v8s*)(Qi + (size_t)qrow * 192 + h * 32 + quad * 8);
        v8s kf[4];
#pragma unroll
        for (int cta = 0; cta < 4; cta++)
          kf[cta] = *(const v8s*)(Kj + (size_t)(cta * 16 + l15) * 192 + h * 32 + quad * 8);
        v4f S[4];
#pragma unroll
        for (int cta = 0; cta < 4; cta++)
          S[cta] = __builtin_amdgcn_mfma_f32_16x16x32_bf16(kf[cta], qa, vzero, 0, 0, 0);
        v8s vf0a = *(const v8s*)(Vj + (size_t)(h * 32 + l15) * 64 + quad * 8);
        v8s vf0b = *(const v8s*)(Vj + (size_t)(h * 32 + l15) * 64 + 32 + quad * 8);
        v8s vf1a = *(const v8s*)(Vj + (size_t)(h * 32 + 16 + l15) * 64 + quad * 8);
        v8s vf1b = *(const v8s*)(Vj + (size_t)(h * 32 + 16 + l15) * 64 + 32 + quad * 8);
        float mx = -1e30f;
#pragma unroll
        for (int cta = 0; cta < 4; cta++)
#pragma unroll
          for (int r = 0; r < 4; r++) mx = fmaxf(mx, S[cta][r]);
        mx = fmaxf(mx, __shfl_xor(mx, 16, 64));
        mx = fmaxf(mx, __shfl_xor(mx, 32, 64));
        float sum = 0.f;
#pragma unroll
        for (int cta = 0; cta < 4; cta++)
#pragma unroll
          for (int r = 0; r < 4; r++) {
            float e = __expf(S[cta][r] - mx);
            S[cta][r] = e; sum += e;
          }
        sum += __shfl_xor(sum, 16, 64);
        sum += __shfl_xor(sum, 32, 64);
        float inv = 1.0f / sum;
        v8s B0, B1;
        ptrans(S, inv, srcA, srcB, hiq, B0, B1);
        v4f o0 = __builtin_amdgcn_mfma_f32_16x16x32_bf16(vf0a, B0, vzero, 0, 0, 0);
        o0 = __builtin_amdgcn_mfma_f32_16x16x32_bf16(vf0b, B1, o0, 0, 0, 0);
        short4 s0;
        s0.x = f2bf(o0[0]); s0.y = f2bf(o0[1]); s0.z = f2bf(o0[2]); s0.w = f2bf(o0[3]);
        *(short4*)(&SP[(qt * 16 + l15) * 200 + h * 32 + quad * 4]) = s0;
        v4f o1 = __builtin_amdgcn_mfma_f32_16x16x32_bf16(vf1a, B0, vzero, 0, 0, 0);
        o1 = __builtin_amdgcn_mfma_f32_16x16x32_bf16(vf1b, B1, o1, 0, 0, 0);
        short4 s1;
        s1.x = f2bf(o1[0]); s1.y = f2bf(o1[1]); s1.z = f2bf(o1[2]); s1.w = f2bf(o1[3]);
        *(short4*)(&SP[(qt * 16 + l15) * 200 + h * 32 + 16 + quad * 4]) = s1;
      }
    }
    __syncthreads();               // B: o ready

    // ---- G1: y1 = Wproj[:,0:192].o^T + Wproj[:,192:384].xi^T ----
    v4f y1[3][2];
#pragma unroll
    for (int cti = 0; cti < 3; cti++)
#pragma unroll
      for (int nt = 0; nt < 2; nt++) y1[cti][nt] = vzero;
#pragma unroll
    for (int ks = 0; ks < 6; ks++) {
      v8s bo[2];
#pragma unroll
      for (int nt = 0; nt < 2; nt++)
        bo[nt] = *(const v8s*)(SP + (nt * 16 + l15) * 200 + ks * 32 + quad * 8);
#pragma unroll
      for (int cti = 0; cti < 3; cti++) {
        v8s a = *(const v8s*)(Wproj_bf + (size_t)(cb + cti * 16 + l15) * 384 + ks * 32 + quad * 8);
#pragma unroll
        for (int nt = 0; nt < 2; nt++)
          y1[cti][nt] = __builtin_amdgcn_mfma_f32_16x16x32_bf16(a, bo[nt], y1[cti][nt], 0, 0, 0);
      }
    }
#pragma unroll
    for (int ks = 0; ks < 6; ks++) {
      // xi fragments rebuilt per-lane from global x (bf16 of x.view rows)
      v8s bx0, bx1;
      {
        const float* p0 = xr0 + ks * 32 + quad * 8;
        const float* p1 = xr1 + ks * 32 + quad * 8;
        v8s r0, r1;
#pragma unroll
        for (int e = 0; e < 8; e++) { r0[e] = f2bf(p0[e]); r1[e] = f2bf(p1[e]); }
        bx0 = r0; bx1 = r1;
      }
#pragma unroll
      for (int cti = 0; cti < 3; cti++) {
        v8s a = *(const v8s*)(Wproj_bf + (size_t)(cb + cti * 16 + l15) * 384 + 192 + ks * 32 + quad * 8);
        y1[cti][0] = __builtin_amdgcn_mfma_f32_16x16x32_bf16(a, bx0, y1[cti][0], 0, 0, 0);
        y1[cti][1] = __builtin_amdgcn_mfma_f32_16x16x32_bf16(a, bx1, y1[cti][1], 0, 0, 0);
      }
    }
    // + bproj; LN partials
#pragma unroll
    for (int cti = 0; cti < 3; cti++) {
      float4 bp4 = *(const float4*)(bproj + cb + cti * 16 + quad * 4);
#pragma unroll
      for (int nt = 0; nt < 2; nt++) {
        y1[cti][nt][0] += bp4.x; y1[cti][nt][1] += bp4.y;
        y1[cti][nt][2] += bp4.z; y1[cti][nt][3] += bp4.w;
      }
    }
#pragma unroll
    for (int nt = 0; nt < 2; nt++) {
      float s1 = 0.f, s2 = 0.f;
#pragma unroll
      for (int cti = 0; cti < 3; cti++)
#pragma unroll
        for (int r = 0; r < 4; r++) { float v = y1[cti][nt][r]; s1 += v; s2 += v * v; }
      s1 += __shfl_xor(s1, 16, 64); s2 += __shfl_xor(s2, 16, 64);
      s1 += __shfl_xor(s1, 32, 64); s2 += __shfl_xor(s2, 32, 64);
      if (quad == 0) {
        LNp[nt * 16 + l15][wc][0] = s1;
        LNp[nt * 16 + l15][wc][1] = s2;
      }
    }
    __syncthreads();               // C: partials visible; G1 SP reads done
    float mu[2], rs[2];
#pragma unroll
    for (int nt = 0; nt < 2; nt++) {
      int row = nt * 16 + l15;
      float s1 = 0.f, s2 = 0.f;
#pragma unroll
      for (int ww = 0; ww < 4; ww++) { s1 += LNp[row][ww][0]; s2 += LNp[row][ww][1]; }
      float m = s1 * (1.0f / 192.0f);
      mu[nt] = m; rs[nt] = rsqrtf(s2 * (1.0f / 192.0f) - m * m + 1e-5f);
    }
#pragma unroll
    for (int cti = 0; cti < 3; cti++) {
      float4 g4 = *(const float4*)(gamma + cb + cti * 16 + quad * 4);
      float4 be4 = *(const float4*)(beta + cb + cti * 16 + quad * 4);
#pragma unroll
      for (int nt = 0; nt < 2; nt++) {
        short4 s;
        s.x = f2bf((y1[cti][nt][0] - mu[nt]) * rs[nt] * g4.x + be4.x);
        s.y = f2bf((y1[cti][nt][1] - mu[nt]) * rs[nt] * g4.y + be4.y);
        s.z = f2bf((y1[cti][nt][2] - mu[nt]) * rs[nt] * g4.z + be4.z);
        s.w = f2bf((y1[cti][nt][3] - mu[nt]) * rs[nt] * g4.w + be4.w);
        *(short4*)(&SP[(nt * 16 + l15) * 200 + cb + cti * 16 + quad * 4]) = s;
      }
    }
    __syncthreads();               // D: y1n ready

    // ---- G2: y2 = W1 . y1n^T ; gelu -> HB ----
    v4f y2[3][2];
#pragma unroll
    for (int cti = 0; cti < 3; cti++)
#pragma unroll
      for (int nt = 0; nt < 2; nt++) y2[cti][nt] = vzero;
#pragma unroll
    for (int ks = 0; ks < 6; ks++) {
      v8s bh[2];
#pragma unroll
      for (int nt = 0; nt < 2; nt++)
        bh[nt] = *(const v8s*)(SP + (nt * 16 + l15) * 200 + ks * 32 + quad * 8);
#pragma unroll
      for (int cti = 0; cti < 3; cti++) {
        v8s a = *(const v8s*)(W1_bf + (size_t)(cb + cti * 16 + l15) * 192 + ks * 32 + quad * 8);
#pragma unroll
        for (int nt = 0; nt < 2; nt++)
          y2[cti][nt] = __builtin_amdgcn_mfma_f32_16x16x32_bf16(a, bh[nt], y2[cti][nt], 0, 0, 0);
      }
    }
#pragma unroll
    for (int cti = 0; cti < 3; cti++) {
      float4 b14 = *(const float4*)(b1 + cb + cti * 16 + quad * 4);
#pragma unroll
      for (int nt = 0; nt < 2; nt++) {
        float vv[4] = {y2[cti][nt][0] + b14.x, y2[cti][nt][1] + b14.y,
                       y2[cti][nt][2] + b14.z, y2[cti][nt][3] + b14.w};
        short sv[4];
#pragma unroll
        for (int r = 0; r < 4; r++) {
          float v = vv[r];
          float t = 0.79788456080286536f * (v + 0.044715f * v * v * v);
          float e = __expf(2.0f * t);
          float th = 1.0f - 2.0f / (e + 1.0f);
          sv[r] = f2bf(0.5f * v * (1.0f + th));
        }
        short4 s;
        s.x = sv[0]; s.y = sv[1]; s.z = sv[2]; s.w = sv[3];
        *(short4*)(&HB[(nt * 16 + l15) * 200 + cb + cti * 16 + quad * 4]) = s;
      }
    }
    __syncthreads();               // E: h ready; G2 SP reads done

    // ---- G3: acc += W2 . h^T (from HB) ----
#pragma unroll
    for (int ks = 0; ks < 6; ks++) {
      v8s bh[2];
#pragma unroll
      for (int nt = 0; nt < 2; nt++)
        bh[nt] = *(const v8s*)(HB + (nt * 16 + l15) * 200 + ks * 32 + quad * 8);
#pragma unroll
      for (int cti = 0; cti < 3; cti++) {
        v8s a = *(const v8s*)(W2_bf + (size_t)(cb + cti * 16 + l15) * 192 + ks * 32 + quad * 8);
#pragma unroll
        for (int nt = 0; nt < 2; nt++)
          acc[cti][nt] = __builtin_amdgcn_mfma_f32_16x16x32_bf16(a, bh[nt], acc[cti][nt], 0, 0, 0);
      }
    }
  }

  // ---- epilogue: stage acc/6 to LDS (f32), write full contiguous rows ----
  float* SPf = (float*)SP;
#pragma unroll
  for (int pass = 0; pass < 2; pass++) {
    __syncthreads();               // SP/HB reads done (pass 0) / prior pass copy done
#pragma unroll
    for (int cti = 0; cti < 3; cti++) {
      float4 o4;
      o4.x = acc[cti][pass][0] * (1.0f / 6.0f);
      o4.y = acc[cti][pass][1] * (1.0f / 6.0f);
      o4.z = acc[cti][pass][2] * (1.0f / 6.0f);
      o4.w = acc[cti][pass][3] * (1.0f / 6.0f);
      *(float4*)(&SPf[l15 * 196 + cb + cti * 16 + quad * 4]) = o4;
    }
    __syncthreads();
    for (int c = tid; c < 768; c += 256) {
      int r16 = c / 48, col4 = (c - r16 * 48) * 4;
      int row = half * 32 + pass * 16 + r16;
      size_t nrow = (size_t)b * 384 + (size_t)i * 64 + row;
      float4 xv = *(const float4*)(x + nrow * DIM + col4);
      float4 b24 = *(const float4*)(b2 + col4);
      float4 av = *(const float4*)(&SPf[r16 * 196 + col4]);
      float4 o4;
      o4.x = xv.x + av.x + b24.x;
      o4.y = xv.y + av.y + b24.y;
      o4.z = xv.z + av.z + b24.z;
      o4.w = xv.w + av.w + b24.w;
      *(float4*)(out + nrow * 384 + col4) = xv;             // x half bit-exact
      *(float4*)(out + nrow * 384 + 192 + col4) = o4;
    }
  }
}

extern "C" void kernel_launch(void* const* d_in, const int* in_sizes, int n_in,
                              void* d_out, int out_size, void* d_ws, size_t ws_size,
                              hipStream_t stream) {
  (void)in_sizes; (void)n_in; (void)out_size; (void)ws_size;
  const float* x     = (const float*)d_in[0];
  const float* Wqkv  = (const float*)d_in[1];
  const float* Wproj = (const float*)d_in[2];
  const float* bproj = (const float*)d_in[3];
  const float* gamma = (const float*)d_in[4];
  const float* beta  = (const float*)d_in[5];
  const float* W1    = (const float*)d_in[6];
  const float* b1    = (const float*)d_in[7];
  const float* W2    = (const float*)d_in[8];
  const float* b2    = (const float*)d_in[9];
  float* out = (float*)d_out;

  // workspace: weights bf16 + pos f32 + Q/K/Vt bf16
  short* Wqkv_bf  = (short*)d_ws;                 // 576*192
  short* Wproj_bf = Wqkv_bf + 110592;             // 192*384
  short* W1_bf    = Wproj_bf + 73728;             // 192*192
  short* W2_bf    = W1_bf + 36864;                // 192*192
  float* pos_f    = (float*)(W2_bf + 36864);      // 64*192 f32
  short* Qb       = (short*)(pos_f + 12288);      // [b][t][hw][ch]
  short* Kb       = Qb + 9437184;                 // [b][t][hw][ch]
  short* Vtb      = Kb + 9437184;                 // [b][t][ch][hw]

  prep_kernel<<<dim3(264), dim3(256), 0, stream>>>(
      Wqkv, Wproj, W1, W2, Wqkv_bf, Wproj_bf, W1_bf, W2_bf, pos_f);
  qkv_kernel<<<dim3(TT * NB), dim3(256), 0, stream>>>(x, pos_f, Wqkv_bf, Qb, Kb, Vtb);
  fused_all<<<dim3(TT * NB * 2), dim3(256), 0, stream>>>(
      x, Qb, Kb, Vtb, Wproj_bf, W1_bf, W2_bf, bproj, gamma, beta, b1, b2, out);
}